// Round 4
// baseline (1422.234 us; speedup 1.0000x reference)
//
#include <hip/hip_runtime.h>
#include <math.h>

// RPMNet registration, fully fused: 1 zero-kernel + 1 persistent kernel.
// B=16, N=1024, feat 6. 3 reg iters x 5 sinkhorn iters, dual-potential form,
// base-2 log domain. Each wave owns 8 src rows + 8 ref cols (features in VGPRs);
// potentials live in slot 7 of the packed [B][N][8] arrays. Per-batch spin
// barriers (32 blocks/batch) replace kernel-boundary syncs.
// Launch: try cooperative (co-residency guaranteed); on error fall back to a
// regular 512-block launch — __launch_bounds__(256,2) => 2 blocks/CU => all
// 512 co-resident there too.
//
// ws layout (floats): [0..255] T(16x12 pad) | [256..511] accum(16x16)
//                     [512..1023 as u32] bar(16 x 32-u32 stride)
//                     [1024..] fr(16*1024*8) | fs(16*1024*8)

#define BATCH 16
#define NPTS  1024
#define REG_ITERS 3
#define SK_ITERS  5
#define EPS 1e-5f
#define LOG2E 1.44269504088896f

struct Feat8 { float x[8], y[8], z[8], a[8], b[8], c[8], cr[8]; };

__device__ __forceinline__ void batch_barrier(unsigned* bar, unsigned target) {
    __syncthreads();
    if (threadIdx.x == 0) {
        __threadfence();  // agent-scope release: publish my block's global writes
        __hip_atomic_fetch_add(bar, 1u, __ATOMIC_RELEASE, __HIP_MEMORY_SCOPE_AGENT);
        while (__hip_atomic_load(bar, __ATOMIC_ACQUIRE, __HIP_MEMORY_SCOPE_AGENT) < target)
            __builtin_amdgcn_s_sleep(1);
    }
    __syncthreads();
}

// one streaming pass: out[r] = log2(1 + sum_k exp2(tb2*dot - bet2*sq_k - vscale*pot_k + cr[r]))
__device__ __forceinline__ void pot_pass(const Feat8& F, const float* __restrict__ ob,
                                         float bet2, float tb2, float vscale, int lane,
                                         float out[8]) {
    float acc[8];
    #pragma unroll
    for (int r = 0; r < 8; ++r) acc[r] = 0.f;
    for (int k = lane; k < NPTS; k += 64) {
        const float4* op = (const float4*)(ob + (size_t)k * 8);
        float4 r0 = op[0], r1 = op[1];
        float tk = fmaf(bet2, r1.z, vscale * r1.w);
        #pragma unroll
        for (int r = 0; r < 8; ++r) {
            float d = F.x[r]*r0.x + F.y[r]*r0.y + F.z[r]*r0.z
                    + F.a[r]*r0.w + F.b[r]*r1.x + F.c[r]*r1.y;
            acc[r] += __builtin_amdgcn_exp2f(fmaf(tb2, d, F.cr[r] - tk));
        }
    }
    #pragma unroll
    for (int r = 0; r < 8; ++r) {
        float a = acc[r];
        for (int off = 32; off; off >>= 1) a += __shfl_down(a, off);
        a = __shfl(a, 0);
        out[r] = __builtin_amdgcn_logf(1.f + a);   // v_log_f32 = log2
    }
}

__global__ void zero_kernel(float* ws) {
    int t = threadIdx.x;                 // 256 threads
    ws[256 + t] = 0.f;                   // accum
    ((unsigned*)ws)[512 + t] = 0u;       // bar lo
    ((unsigned*)ws)[768 + t] = 0u;       // bar hi
}

__global__ __launch_bounds__(256, 2) void rpm_kernel(
        const float* __restrict__ psrc, const float* __restrict__ pref,
        const float* __restrict__ beta, const float* __restrict__ alpha,
        float* __restrict__ ws, float* __restrict__ outT, float* __restrict__ perm)
{
    float*    T      = ws;
    float*    accum  = ws + 256;
    unsigned* barb   = (unsigned*)ws + 512;
    float*    fr     = ws + 1024;
    float*    fs     = fr + BATCH * NPTS * 8;

    const int blk  = blockIdx.x;
    const int b    = blk & 15;                 // all 32 blocks of a batch: same XCD (blk%8 const)
    const int sub  = blk >> 4;                 // 0..31
    const int wid  = threadIdx.x >> 6, lane = threadIdx.x & 63;
    const int rbase = (sub << 5) + (wid << 3); // 0..1023 step 8
    const int grow  = (b << 10) + rbase;

    unsigned* mybar = barb + b * 32;           // 128B stride
    unsigned  phase = 0;

    const float bet2 = beta[b] * LOG2E;
    const float alp  = alpha[b];
    const float tb2  = 2.f * bet2;

    // ---- init own ref cols -> regs + store to fr (slot7 = v placeholder)
    Feat8 C;
    #pragma unroll
    for (int r = 0; r < 8; ++r) {
        const float* p = pref + (size_t)(grow + r) * 6;
        float x = p[0], y = p[1], z = p[2], a = p[3], bb = p[4], c = p[5];
        float sq = x*x + y*y + z*z + a*a + bb*bb + c*c;
        C.x[r]=x; C.y[r]=y; C.z[r]=z; C.a[r]=a; C.b[r]=bb; C.c[r]=c;
        C.cr[r] = bet2 * (alp - sq);
        if (lane == 0) {
            float* o = fr + (size_t)(grow + r) * 8;
            *(float4*)o       = make_float4(x, y, z, a);
            *(float4*)(o + 4) = make_float4(bb, c, sq, 0.f);
        }
    }
    batch_barrier(mybar, 32u * (++phase));     // fr visible batch-wide

    const float* frb = fr + ((size_t)b << 10) * 8;
    const float* fsb = fs + ((size_t)b << 10) * 8;

    Feat8 Rw;
    float u[8];

    for (int it = 0; it < REG_ITERS; ++it) {
        const bool last = (it == REG_ITERS - 1);

        // ---- A) own src rows: transform by current T, regs + store to fs
        float t00,t01,t02,t03,t10,t11,t12,t13,t20,t21,t22,t23;
        if (it == 0) {
            t00=1;t01=0;t02=0;t03=0; t10=0;t11=1;t12=0;t13=0; t20=0;t21=0;t22=1;t23=0;
        } else {
            const float* t = T + b * 12;
            t00=t[0];t01=t[1];t02=t[2];t03=t[3];
            t10=t[4];t11=t[5];t12=t[6];t13=t[7];
            t20=t[8];t21=t[9];t22=t[10];t23=t[11];
        }
        #pragma unroll
        for (int r = 0; r < 8; ++r) {
            const float* p = psrc + (size_t)(grow + r) * 6;
            float x = p[0], y = p[1], z = p[2];
            float tx = t00*x + t01*y + t02*z + t03;
            float ty = t10*x + t11*y + t12*z + t13;
            float tz = t20*x + t21*y + t22*z + t23;
            float f3 = p[3], f4 = p[4], f5 = p[5];
            float sq = tx*tx + ty*ty + tz*tz + f3*f3 + f4*f4 + f5*f5;
            Rw.x[r]=tx; Rw.y[r]=ty; Rw.z[r]=tz; Rw.a[r]=f3; Rw.b[r]=f4; Rw.c[r]=f5;
            Rw.cr[r] = bet2 * (alp - sq);
            if (lane == 0) {
                float* o = fs + (size_t)(grow + r) * 8;
                *(float4*)o       = make_float4(tx, ty, tz, f3);
                *(float4*)(o + 4) = make_float4(f4, f5, sq, 0.f);
            }
        }
        // no barrier: u-pass reads only own rows (regs) + fr; fs stores are
        // published by the barrier that follows the u-pass potential store.

        // ---- B) 5 x (u-pass, v-pass)
        for (int sk = 0; sk < SK_ITERS; ++sk) {
            pot_pass(Rw, frb, bet2, tb2, (sk == 0) ? 0.f : 1.f, lane, u);
            if (lane == 0) {
                #pragma unroll
                for (int r = 0; r < 8; ++r) fs[(size_t)(grow + r) * 8 + 7] = u[r];
            }
            batch_barrier(mybar, 32u * (++phase));
            float v[8];
            pot_pass(C, fsb, bet2, tb2, 1.f, lane, v);
            if (lane == 0) {
                #pragma unroll
                for (int r = 0; r < 8; ++r) fr[(size_t)(grow + r) * 8 + 7] = v[r];
            }
            batch_barrier(mybar, 32u * (++phase));
        }

        // ---- C) finalize: per-row sums, batch accumulators, perm on last iter
        float pS[16];
        #pragma unroll
        for (int i = 0; i < 16; ++i) pS[i] = 0.f;
        for (int r = 0; r < 8; ++r) {
            float s = 0.f, sx = 0.f, sy = 0.f, sz = 0.f;
            const float cru = Rw.cr[r] - u[r];
            const float fx = Rw.x[r], fy = Rw.y[r], fz = Rw.z[r];
            const float f3 = Rw.a[r], f4 = Rw.b[r], f5 = Rw.c[r];
            for (int k = lane; k < NPTS; k += 64) {
                const float4* op = (const float4*)(frb + (size_t)k * 8);
                float4 r0 = op[0], r1 = op[1];
                float d = fx*r0.x + fy*r0.y + fz*r0.z + f3*r0.w + f4*r1.x + f5*r1.y;
                float p = __builtin_amdgcn_exp2f(fmaf(tb2, d, cru - fmaf(bet2, r1.z, r1.w)));
                s += p; sx += p*r0.x; sy += p*r0.y; sz += p*r0.z;
                if (last) perm[(size_t)(grow + r) * NPTS + k] = p;
            }
            for (int off = 32; off; off >>= 1) {
                s  += __shfl_down(s,  off);
                sx += __shfl_down(sx, off);
                sy += __shfl_down(sy, off);
                sz += __shfl_down(sz, off);
            }
            if (lane == 0) {
                float inv = 1.f / (s + EPS);
                float bx = sx*inv, by = sy*inv, bz = sz*inv;
                pS[0] += s;
                pS[1] += s*fx;  pS[2] += s*fy;  pS[3] += s*fz;
                pS[4] += s*bx;  pS[5] += s*by;  pS[6] += s*bz;
                pS[7] += s*fx*bx;  pS[8]  += s*fx*by;  pS[9]  += s*fx*bz;
                pS[10]+= s*fy*bx;  pS[11] += s*fy*by;  pS[12] += s*fy*bz;
                pS[13]+= s*fz*bx;  pS[14] += s*fz*by;  pS[15] += s*fz*bz;
            }
        }
        if (lane == 0) {
            #pragma unroll
            for (int i = 0; i < 16; ++i) atomicAdd(&accum[b * 16 + i], pS[i]);
        }
        batch_barrier(mybar, 32u * (++phase));

        // ---- D) rigid: one thread per batch (Kabsch via double Jacobi SVD)
        if (sub == 0 && threadIdx.x == 0) {
            float* ac = accum + b * 16;
            double Sw = ac[0];
            double Sa[3] = {ac[1], ac[2], ac[3]};
            double Sb[3] = {ac[4], ac[5], ac[6]};
            double D  = Sw + (double)EPS;
            double ca0 = Sa[0]/D, ca1 = Sa[1]/D, ca2 = Sa[2]/D;
            double cb0 = Sb[0]/D, cb1 = Sb[1]/D, cb2 = Sb[2]/D;
            double f  = (2.0 - Sw / D) / D;
            double Am[3][3];
            for (int m = 0; m < 3; ++m)
                for (int n = 0; n < 3; ++n)
                    Am[m][n] = (double)ac[7 + m*3 + n] - f * Sa[m] * Sb[n];
            // S = Am^T Am, Jacobi eigendecomposition
            double S[3][3];
            for (int i = 0; i < 3; ++i)
                for (int j = 0; j < 3; ++j) {
                    double acc2 = 0;
                    for (int m = 0; m < 3; ++m) acc2 += Am[m][i] * Am[m][j];
                    S[i][j] = acc2;
                }
            double V[3][3] = {{1,0,0},{0,1,0},{0,0,1}};
            const int prr[3] = {0,0,1}, qrr[3] = {1,2,2};
            for (int sweep = 0; sweep < 25; ++sweep) {
                double off = S[0][1]*S[0][1] + S[0][2]*S[0][2] + S[1][2]*S[1][2];
                if (off < 1e-28) break;
                for (int pi = 0; pi < 3; ++pi) {
                    int p = prr[pi], q = qrr[pi];
                    double apq = S[p][q];
                    if (fabs(apq) < 1e-300) continue;
                    double theta = (S[q][q] - S[p][p]) / (2.0 * apq);
                    double tt = ((theta >= 0) ? 1.0 : -1.0) / (fabs(theta) + sqrt(theta*theta + 1.0));
                    double cth = 1.0 / sqrt(tt*tt + 1.0), sth = tt * cth;
                    for (int m = 0; m < 3; ++m) { double a1=S[m][p], a2=S[m][q]; S[m][p]=cth*a1-sth*a2; S[m][q]=sth*a1+cth*a2; }
                    for (int m = 0; m < 3; ++m) { double a1=S[p][m], a2=S[q][m]; S[p][m]=cth*a1-sth*a2; S[q][m]=sth*a1+cth*a2; }
                    for (int m = 0; m < 3; ++m) { double a1=V[m][p], a2=V[m][q]; V[m][p]=cth*a1-sth*a2; V[m][q]=sth*a1+cth*a2; }
                }
            }
            double lam[3] = {S[0][0], S[1][1], S[2][2]};
            int idx[3] = {0,1,2};
            if (lam[idx[0]] < lam[idx[1]]) { int t2=idx[0]; idx[0]=idx[1]; idx[1]=t2; }
            if (lam[idx[0]] < lam[idx[2]]) { int t2=idx[0]; idx[0]=idx[2]; idx[2]=t2; }
            if (lam[idx[1]] < lam[idx[2]]) { int t2=idx[1]; idx[1]=idx[2]; idx[2]=t2; }
            double Vs[3][3], sv[3];
            for (int i = 0; i < 3; ++i) {
                int c = idx[i];
                for (int m = 0; m < 3; ++m) Vs[m][i] = V[m][c];
                double l = lam[c]; sv[i] = sqrt(l > 0 ? l : 0);
            }
            double Us[3][3] = {{1,0,0},{0,1,0},{0,0,1}};  // defensive init
            double smax = sv[0] > 1e-300 ? sv[0] : 1e-300;
            for (int i = 0; i < 3; ++i) {
                double ux = Am[0][0]*Vs[0][i] + Am[0][1]*Vs[1][i] + Am[0][2]*Vs[2][i];
                double uy = Am[1][0]*Vs[0][i] + Am[1][1]*Vs[1][i] + Am[1][2]*Vs[2][i];
                double uz = Am[2][0]*Vs[0][i] + Am[2][1]*Vs[1][i] + Am[2][2]*Vs[2][i];
                if (sv[i] > 1e-12 * smax) {
                    Us[0][i] = ux/sv[i]; Us[1][i] = uy/sv[i]; Us[2][i] = uz/sv[i];
                } else if (i == 2) {
                    double cx = Us[1][0]*Us[2][1] - Us[2][0]*Us[1][1];
                    double cy = Us[2][0]*Us[0][1] - Us[0][0]*Us[2][1];
                    double cz = Us[0][0]*Us[1][1] - Us[1][0]*Us[0][1];
                    double n = sqrt(cx*cx + cy*cy + cz*cz); n = n > 1e-300 ? n : 1.0;
                    Us[0][i] = cx/n; Us[1][i] = cy/n; Us[2][i] = cz/n;
                }
            }
            double M[3][3];
            for (int m = 0; m < 3; ++m)
                for (int n = 0; n < 3; ++n)
                    M[m][n] = Vs[m][0]*Us[n][0] + Vs[m][1]*Us[n][1] + Vs[m][2]*Us[n][2];
            double det = M[0][0]*(M[1][1]*M[2][2]-M[1][2]*M[2][1])
                       - M[0][1]*(M[1][0]*M[2][2]-M[1][2]*M[2][0])
                       + M[0][2]*(M[1][0]*M[2][1]-M[1][1]*M[2][0]);
            double g3 = (det > 0.0) ? 1.0 : -1.0;
            double R[3][3];
            for (int m = 0; m < 3; ++m)
                for (int n = 0; n < 3; ++n)
                    R[m][n] = Vs[m][0]*Us[n][0] + Vs[m][1]*Us[n][1] + g3*Vs[m][2]*Us[n][2];
            double ti[3];
            ti[0] = -(R[0][0]*ca0 + R[0][1]*ca1 + R[0][2]*ca2) + cb0;
            ti[1] = -(R[1][0]*ca0 + R[1][1]*ca1 + R[1][2]*ca2) + cb1;
            ti[2] = -(R[2][0]*ca0 + R[2][1]*ca1 + R[2][2]*ca2) + cb2;
            // compose with previous transform
            float* Tb = T + b * 12;
            double Ro[3][3], to[3];
            if (it == 0) {
                Ro[0][0]=1;Ro[0][1]=0;Ro[0][2]=0; Ro[1][0]=0;Ro[1][1]=1;Ro[1][2]=0;
                Ro[2][0]=0;Ro[2][1]=0;Ro[2][2]=1; to[0]=to[1]=to[2]=0;
            } else {
                Ro[0][0]=Tb[0];Ro[0][1]=Tb[1];Ro[0][2]=Tb[2];  to[0]=Tb[3];
                Ro[1][0]=Tb[4];Ro[1][1]=Tb[5];Ro[1][2]=Tb[6];  to[1]=Tb[7];
                Ro[2][0]=Tb[8];Ro[2][1]=Tb[9];Ro[2][2]=Tb[10]; to[2]=Tb[11];
            }
            float Tn[12];
            for (int m = 0; m < 3; ++m) {
                for (int n = 0; n < 3; ++n)
                    Tn[m*4+n] = (float)(R[m][0]*Ro[0][n] + R[m][1]*Ro[1][n] + R[m][2]*Ro[2][n]);
                Tn[m*4+3] = (float)(R[m][0]*to[0] + R[m][1]*to[1] + R[m][2]*to[2] + ti[m]);
            }
            for (int i = 0; i < 12; ++i) Tb[i] = Tn[i];
            if (last) for (int i = 0; i < 12; ++i) outT[b*12+i] = Tn[i];
            for (int i = 0; i < 16; ++i) ac[i] = 0.f;   // reset for next reg iter
        }
        batch_barrier(mybar, 32u * (++phase));
    }
}

extern "C" void kernel_launch(void* const* d_in, const int* in_sizes, int n_in,
                              void* d_out, int out_size, void* d_ws, size_t ws_size,
                              hipStream_t stream) {
    const float* psrc  = (const float*)d_in[0];
    const float* pref  = (const float*)d_in[1];
    const float* beta  = (const float*)d_in[2];
    const float* alpha = (const float*)d_in[3];

    float* out     = (float*)d_out;
    float* outT    = out;            // (16,3,4)
    float* outPerm = out + 192;      // (16,1024,1024)
    float* ws      = (float*)d_ws;

    zero_kernel<<<1, 256, 0, stream>>>(ws);

    void* args[] = { (void*)&psrc, (void*)&pref, (void*)&beta, (void*)&alpha,
                     (void*)&ws, (void*)&outT, (void*)&outPerm };
    hipError_t ce = hipLaunchCooperativeKernel((const void*)rpm_kernel, dim3(512), dim3(256),
                                               args, 0, stream);
    if (ce != hipSuccess) {
        // Fallback: regular launch. __launch_bounds__(256,2) => 2 blocks/CU =>
        // all 512 blocks co-resident; per-batch spin barriers remain safe.
        rpm_kernel<<<dim3(512), dim3(256), 0, stream>>>(psrc, pref, beta, alpha,
                                                        ws, outT, outPerm);
    }
}

// Round 5
// 567.986 us; speedup vs baseline: 2.5040x; 2.5040x over previous
//
#include <hip/hip_runtime.h>
#include <math.h>

// RPMNet registration, fused persistent kernel with ZERO cache-maintenance sync.
// B=16, N=1024, feat 6; 3 reg iters x 5 sinkhorn iters (dual-potential, base-2 log).
// Cross-block data (u, v, accum, barrier counters) moves ONLY via relaxed
// agent-scope atomics (coherent-point ops, no wbl2/inv). Features are
// block-private: ref + T-transformed src in per-block LDS (stride 9 floats =
// bank-conflict-free), rebuilt from read-only inputs. SVD computed redundantly
// per block from identical accum bits -> identical T, no broadcast barrier.
//
// ws (floats): [0..767] accum[3][16][16] (prep-zeroed) | [1024..1535] barriers
//              (u32, 16 batches x 32-u32 stride, prep-zeroed) | [1536..] u[16][1024]
//              | then v[16][1024]  (u/v poison-safe: written before first read)

#define BATCH 16
#define NPTS  1024
#define REG_ITERS 3
#define SK_ITERS  5
#define EPS 1e-5f
#define LOG2E 1.44269504088896f
#define LSTR  9          // LDS floats per point (odd => conflict-free)

#define WS_ACCUM 0
#define WS_BAR   1024
#define WS_U     1536
#define WS_V     (1536 + BATCH * NPTS)

struct F8 { float x[8], y[8], z[8], p[8], q[8], w[8], cr[8]; };

__device__ __forceinline__ float ld_pot(const float* p) {
    return __hip_atomic_load((float*)p, __ATOMIC_RELAXED, __HIP_MEMORY_SCOPE_AGENT);
}
__device__ __forceinline__ void st_pot(float* p, float v) {
    __hip_atomic_store(p, v, __ATOMIC_RELAXED, __HIP_MEMORY_SCOPE_AGENT);
}

// relaxed spin barrier: no acquire/release cache ops. __syncthreads drains each
// thread's vmcnt (incl. sc-flagged stores -> coherent point) before the signal.
__device__ __forceinline__ void batch_barrier(unsigned* bar, unsigned target) {
    __syncthreads();
    if (threadIdx.x == 0) {
        __builtin_amdgcn_s_waitcnt(0);
        __hip_atomic_fetch_add(bar, 1u, __ATOMIC_RELAXED, __HIP_MEMORY_SCOPE_AGENT);
        while (__hip_atomic_load(bar, __ATOMIC_RELAXED, __HIP_MEMORY_SCOPE_AGENT) < target)
            __builtin_amdgcn_s_sleep(2);
    }
    __syncthreads();
    __asm__ __volatile__("" ::: "memory");
}

template <bool USEPOT>
__device__ __forceinline__ void pot_pass(const F8& F, const float* __restrict__ lds,
                                         const float* pot, float bet2, float tb2,
                                         int lane, float out[8]) {
    float acc[8];
    #pragma unroll
    for (int r = 0; r < 8; ++r) acc[r] = 0.f;
    #pragma unroll 4
    for (int k = lane; k < NPTS; k += 64) {
        const float* L = lds + k * LSTR;
        float r0=L[0], r1=L[1], r2=L[2], r3=L[3], r4=L[4], r5=L[5], sq=L[6];
        float tk;
        if (USEPOT) tk = fmaf(bet2, sq, ld_pot(pot + k));
        else        tk = bet2 * sq;
        #pragma unroll
        for (int r = 0; r < 8; ++r) {
            float d = F.x[r]*r0 + F.y[r]*r1 + F.z[r]*r2
                    + F.p[r]*r3 + F.q[r]*r4 + F.w[r]*r5;
            acc[r] += __builtin_amdgcn_exp2f(fmaf(tb2, d, F.cr[r] - tk));
        }
    }
    #pragma unroll
    for (int r = 0; r < 8; ++r) {
        float a = acc[r];
        for (int off = 32; off; off >>= 1) a += __shfl_down(a, off);
        out[r] = __builtin_amdgcn_logf(1.f + __shfl(a, 0));   // v_log_f32 = log2
    }
}

// weighted Kabsch from 16 accum moments + old T -> new T (12 floats)
__device__ void kabsch_svd(const float* ac, const float* Told, float* Tnew) {
    double Sw = ac[0];
    double Sa[3] = {ac[1], ac[2], ac[3]};
    double Sb[3] = {ac[4], ac[5], ac[6]};
    double D  = Sw + (double)EPS;
    double ca0 = Sa[0]/D, ca1 = Sa[1]/D, ca2 = Sa[2]/D;
    double cb0 = Sb[0]/D, cb1 = Sb[1]/D, cb2 = Sb[2]/D;
    double f  = (2.0 - Sw / D) / D;
    double Am[3][3];
    for (int m = 0; m < 3; ++m)
        for (int n = 0; n < 3; ++n)
            Am[m][n] = (double)ac[7 + m*3 + n] - f * Sa[m] * Sb[n];
    double S[3][3];
    for (int i = 0; i < 3; ++i)
        for (int j = 0; j < 3; ++j) {
            double a2 = 0;
            for (int m = 0; m < 3; ++m) a2 += Am[m][i] * Am[m][j];
            S[i][j] = a2;
        }
    double V[3][3] = {{1,0,0},{0,1,0},{0,0,1}};
    const int prr[3] = {0,0,1}, qrr[3] = {1,2,2};
    for (int sweep = 0; sweep < 25; ++sweep) {
        double off = S[0][1]*S[0][1] + S[0][2]*S[0][2] + S[1][2]*S[1][2];
        if (off < 1e-28) break;
        for (int pi = 0; pi < 3; ++pi) {
            int p = prr[pi], q = qrr[pi];
            double apq = S[p][q];
            if (fabs(apq) < 1e-300) continue;
            double theta = (S[q][q] - S[p][p]) / (2.0 * apq);
            double tt = ((theta >= 0) ? 1.0 : -1.0) / (fabs(theta) + sqrt(theta*theta + 1.0));
            double cth = 1.0 / sqrt(tt*tt + 1.0), sth = tt * cth;
            for (int m = 0; m < 3; ++m) { double a1=S[m][p], a2=S[m][q]; S[m][p]=cth*a1-sth*a2; S[m][q]=sth*a1+cth*a2; }
            for (int m = 0; m < 3; ++m) { double a1=S[p][m], a2=S[q][m]; S[p][m]=cth*a1-sth*a2; S[q][m]=sth*a1+cth*a2; }
            for (int m = 0; m < 3; ++m) { double a1=V[m][p], a2=V[m][q]; V[m][p]=cth*a1-sth*a2; V[m][q]=sth*a1+cth*a2; }
        }
    }
    double lam[3] = {S[0][0], S[1][1], S[2][2]};
    int idx[3] = {0,1,2};
    if (lam[idx[0]] < lam[idx[1]]) { int t2=idx[0]; idx[0]=idx[1]; idx[1]=t2; }
    if (lam[idx[0]] < lam[idx[2]]) { int t2=idx[0]; idx[0]=idx[2]; idx[2]=t2; }
    if (lam[idx[1]] < lam[idx[2]]) { int t2=idx[1]; idx[1]=idx[2]; idx[2]=t2; }
    double Vs[3][3], sv[3];
    for (int i = 0; i < 3; ++i) {
        int c = idx[i];
        for (int m = 0; m < 3; ++m) Vs[m][i] = V[m][c];
        double l = lam[c]; sv[i] = sqrt(l > 0 ? l : 0);
    }
    double Us[3][3] = {{1,0,0},{0,1,0},{0,0,1}};
    double smax = sv[0] > 1e-300 ? sv[0] : 1e-300;
    for (int i = 0; i < 3; ++i) {
        double ux = Am[0][0]*Vs[0][i] + Am[0][1]*Vs[1][i] + Am[0][2]*Vs[2][i];
        double uy = Am[1][0]*Vs[0][i] + Am[1][1]*Vs[1][i] + Am[1][2]*Vs[2][i];
        double uz = Am[2][0]*Vs[0][i] + Am[2][1]*Vs[1][i] + Am[2][2]*Vs[2][i];
        if (sv[i] > 1e-12 * smax) {
            Us[0][i] = ux/sv[i]; Us[1][i] = uy/sv[i]; Us[2][i] = uz/sv[i];
        } else if (i == 2) {
            double cx = Us[1][0]*Us[2][1] - Us[2][0]*Us[1][1];
            double cy = Us[2][0]*Us[0][1] - Us[0][0]*Us[2][1];
            double cz = Us[0][0]*Us[1][1] - Us[1][0]*Us[0][1];
            double n = sqrt(cx*cx + cy*cy + cz*cz); n = n > 1e-300 ? n : 1.0;
            Us[0][i] = cx/n; Us[1][i] = cy/n; Us[2][i] = cz/n;
        }
    }
    double M[3][3];
    for (int m = 0; m < 3; ++m)
        for (int n = 0; n < 3; ++n)
            M[m][n] = Vs[m][0]*Us[n][0] + Vs[m][1]*Us[n][1] + Vs[m][2]*Us[n][2];
    double det = M[0][0]*(M[1][1]*M[2][2]-M[1][2]*M[2][1])
               - M[0][1]*(M[1][0]*M[2][2]-M[1][2]*M[2][0])
               + M[0][2]*(M[1][0]*M[2][1]-M[1][1]*M[2][0]);
    double g3 = (det > 0.0) ? 1.0 : -1.0;
    double R[3][3];
    for (int m = 0; m < 3; ++m)
        for (int n = 0; n < 3; ++n)
            R[m][n] = Vs[m][0]*Us[n][0] + Vs[m][1]*Us[n][1] + g3*Vs[m][2]*Us[n][2];
    double ti[3];
    ti[0] = -(R[0][0]*ca0 + R[0][1]*ca1 + R[0][2]*ca2) + cb0;
    ti[1] = -(R[1][0]*ca0 + R[1][1]*ca1 + R[1][2]*ca2) + cb1;
    ti[2] = -(R[2][0]*ca0 + R[2][1]*ca1 + R[2][2]*ca2) + cb2;
    double Ro[3][3] = {{Told[0],Told[1],Told[2]},{Told[4],Told[5],Told[6]},{Told[8],Told[9],Told[10]}};
    double to[3] = {Told[3], Told[7], Told[11]};
    for (int m = 0; m < 3; ++m) {
        for (int n = 0; n < 3; ++n)
            Tnew[m*4+n] = (float)(R[m][0]*Ro[0][n] + R[m][1]*Ro[1][n] + R[m][2]*Ro[2][n]);
        Tnew[m*4+3] = (float)(R[m][0]*to[0] + R[m][1]*to[1] + R[m][2]*to[2] + ti[m]);
    }
}

__global__ __launch_bounds__(256) void prep_kernel(float* ws) {
    int i = blockIdx.x * 256 + threadIdx.x;   // grid 6 x 256 = 1536
    ws[i] = 0.f;                              // accum region + barrier counters
}

__global__ __launch_bounds__(256, 2) void rpm_kernel(
        const float* __restrict__ psrc, const float* __restrict__ pref,
        const float* __restrict__ beta, const float* __restrict__ alpha,
        float* __restrict__ ws, float* __restrict__ outT, float* __restrict__ perm)
{
    __shared__ float refL[NPTS * LSTR];
    __shared__ float srcL[NPTS * LSTR];
    __shared__ float sred[4][16];
    __shared__ float tT[12];

    const int blk = blockIdx.x, b = blk & 15, sub = blk >> 4;
    const int tid = threadIdx.x, wid = tid >> 6, lane = tid & 63;
    const int rbase = (sub << 5) + (wid << 3);
    const int grow  = (b << 10) + rbase;

    float*    accumA = ws + WS_ACCUM;
    unsigned* bar    = (unsigned*)ws + WS_BAR + b * 32;
    float*    uA     = ws + WS_U + (b << 10);
    float*    vA     = ws + WS_V + (b << 10);

    const float bet2 = beta[b] * LOG2E;
    const float alp  = alpha[b];
    const float tb2  = 2.f * bet2;
    unsigned phase = 0;

    // ---- ref features -> LDS (block-private, from read-only input)
    for (int i = tid; i < NPTS; i += 256) {
        const float* p = pref + ((size_t)(b << 10) + i) * 6;
        float x=p[0], y=p[1], z=p[2], aa=p[3], bb=p[4], cc=p[5];
        float sq = x*x + y*y + z*z + aa*aa + bb*bb + cc*cc;
        float* o = refL + i * LSTR;
        o[0]=x; o[1]=y; o[2]=z; o[3]=aa; o[4]=bb; o[5]=cc; o[6]=sq;
    }
    __syncthreads();

    F8 C;
    #pragma unroll
    for (int r = 0; r < 8; ++r) {
        const float* o = refL + (rbase + r) * LSTR;
        C.x[r]=o[0]; C.y[r]=o[1]; C.z[r]=o[2]; C.p[r]=o[3]; C.q[r]=o[4]; C.w[r]=o[5];
        C.cr[r] = bet2 * (alp - o[6]);
    }

    float Tc[12] = {1,0,0,0, 0,1,0,0, 0,0,1,0};

    for (int it = 0; it < REG_ITERS; ++it) {
        const bool last = (it == REG_ITERS - 1);

        // ---- transform src by Tc -> srcL (block-private)
        for (int i = tid; i < NPTS; i += 256) {
            const float* p = psrc + ((size_t)(b << 10) + i) * 6;
            float x=p[0], y=p[1], z=p[2];
            float tx = Tc[0]*x + Tc[1]*y + Tc[2]*z  + Tc[3];
            float ty = Tc[4]*x + Tc[5]*y + Tc[6]*z  + Tc[7];
            float tz = Tc[8]*x + Tc[9]*y + Tc[10]*z + Tc[11];
            float f3=p[3], f4=p[4], f5=p[5];
            float sq = tx*tx + ty*ty + tz*tz + f3*f3 + f4*f4 + f5*f5;
            float* o = srcL + i * LSTR;
            o[0]=tx; o[1]=ty; o[2]=tz; o[3]=f3; o[4]=f4; o[5]=f5; o[6]=sq;
        }
        __syncthreads();

        F8 Rw;
        #pragma unroll
        for (int r = 0; r < 8; ++r) {
            const float* o = srcL + (rbase + r) * LSTR;
            Rw.x[r]=o[0]; Rw.y[r]=o[1]; Rw.z[r]=o[2]; Rw.p[r]=o[3]; Rw.q[r]=o[4]; Rw.w[r]=o[5];
            Rw.cr[r] = bet2 * (alp - o[6]);
        }

        // ---- 5 x (u-pass, v-pass), potentials via bypass atomics only
        float u[8];
        for (int sk = 0; sk < SK_ITERS; ++sk) {
            if (sk == 0) pot_pass<false>(Rw, refL, nullptr, bet2, tb2, lane, u);
            else         pot_pass<true >(Rw, refL, vA,      bet2, tb2, lane, u);
            if (lane == 0) {
                #pragma unroll
                for (int r = 0; r < 8; ++r) st_pot(&uA[rbase + r], u[r]);
            }
            batch_barrier(bar, 32u * (++phase));

            float v[8];
            pot_pass<true>(C, srcL, uA, bet2, tb2, lane, v);
            if (lane == 0) {
                #pragma unroll
                for (int r = 0; r < 8; ++r) st_pot(&vA[rbase + r], v[r]);
            }
            batch_barrier(bar, 32u * (++phase));
        }

        // ---- finalize: row sums + moment accumulators (+ perm on last iter)
        float pS[16];
        #pragma unroll
        for (int i = 0; i < 16; ++i) pS[i] = 0.f;
        for (int r = 0; r < 8; ++r) {
            float s=0.f, sx=0.f, sy=0.f, sz=0.f;
            const float cru = Rw.cr[r] - u[r];
            const float fx=Rw.x[r], fy=Rw.y[r], fz=Rw.z[r];
            const float f3=Rw.p[r], f4=Rw.q[r], f5=Rw.w[r];
            #pragma unroll 4
            for (int k = lane; k < NPTS; k += 64) {
                const float* L = refL + k * LSTR;
                float r0=L[0], r1=L[1], r2=L[2], r3=L[3], r4=L[4], r5=L[5], sq=L[6];
                float vk = ld_pot(&vA[k]);
                float d = fx*r0 + fy*r1 + fz*r2 + f3*r3 + f4*r4 + f5*r5;
                float p = __builtin_amdgcn_exp2f(fmaf(tb2, d, cru - fmaf(bet2, sq, vk)));
                s += p; sx += p*r0; sy += p*r1; sz += p*r2;
                if (last) perm[(size_t)(grow + r) * NPTS + k] = p;
            }
            for (int off = 32; off; off >>= 1) {
                s  += __shfl_down(s,  off);
                sx += __shfl_down(sx, off);
                sy += __shfl_down(sy, off);
                sz += __shfl_down(sz, off);
            }
            if (lane == 0) {
                float inv = 1.f / (s + EPS);
                float bx = sx*inv, by = sy*inv, bz = sz*inv;
                pS[0] += s;
                pS[1] += s*fx;  pS[2] += s*fy;  pS[3] += s*fz;
                pS[4] += s*bx;  pS[5] += s*by;  pS[6] += s*bz;
                pS[7] += s*fx*bx;  pS[8]  += s*fx*by;  pS[9]  += s*fx*bz;
                pS[10]+= s*fy*bx;  pS[11] += s*fy*by;  pS[12] += s*fy*bz;
                pS[13]+= s*fz*bx;  pS[14] += s*fz*by;  pS[15] += s*fz*bz;
            }
        }
        if (lane == 0) {
            #pragma unroll
            for (int i = 0; i < 16; ++i) sred[wid][i] = pS[i];
        }
        __syncthreads();
        float* ac = accumA + it * 256 + b * 16;   // per-reg-iter buffer, pre-zeroed
        if (tid < 16)
            atomicAdd(&ac[tid], sred[0][tid] + sred[1][tid] + sred[2][tid] + sred[3][tid]);
        batch_barrier(bar, 32u * (++phase));

        // ---- SVD: every block computes T from identical accum bits (no broadcast)
        if (!last || sub == 0) {
            if (tid == 0) {
                float acl[16];
                #pragma unroll
                for (int i = 0; i < 16; ++i) acl[i] = ld_pot(&ac[i]);
                kabsch_svd(acl, Tc, tT);
            }
            __syncthreads();
            #pragma unroll
            for (int i = 0; i < 12; ++i) Tc[i] = tT[i];
            if (last && tid == 0) {
                #pragma unroll
                for (int i = 0; i < 12; ++i) outT[b * 12 + i] = Tc[i];
            }
        }
    }
}

extern "C" void kernel_launch(void* const* d_in, const int* in_sizes, int n_in,
                              void* d_out, int out_size, void* d_ws, size_t ws_size,
                              hipStream_t stream) {
    const float* psrc  = (const float*)d_in[0];
    const float* pref  = (const float*)d_in[1];
    const float* beta  = (const float*)d_in[2];
    const float* alpha = (const float*)d_in[3];

    float* out     = (float*)d_out;
    float* outT    = out;            // (16,3,4)
    float* outPerm = out + 192;      // (16,1024,1024)
    float* ws      = (float*)d_ws;

    prep_kernel<<<6, 256, 0, stream>>>(ws);

    void* args[] = { (void*)&psrc, (void*)&pref, (void*)&beta, (void*)&alpha,
                     (void*)&ws, (void*)&outT, (void*)&outPerm };
    hipError_t ce = hipLaunchCooperativeKernel((const void*)rpm_kernel, dim3(512), dim3(256),
                                               args, 0, stream);
    if (ce != hipSuccess) {
        // Regular launch: LDS 74KB + launch_bounds => 2 blocks/CU => all 512
        // blocks co-resident (this path ran fine in R4).
        rpm_kernel<<<dim3(512), dim3(256), 0, stream>>>(psrc, pref, beta, alpha,
                                                        ws, outT, outPerm);
    }
}

// Round 6
// 509.166 us; speedup vs baseline: 2.7933x; 1.1155x over previous
//
#include <hip/hip_runtime.h>
#include <math.h>

// RPMNet registration, fused persistent kernel, linear-domain Sinkhorn.
// B=16, N=1024, feat 6; 3 reg iters x 5 sinkhorn iters.
// K = exp2(aff2) for each block's 32 rows lives in REGISTERS (Kreg[8][16]/lane).
// wu = 1/(1+K@wv), wv = 1/(1+K^T@wu): u-pass is block-local (register FMA);
// v-pass publishes column partials via relaxed agent-scope fp32 atomicAdd into
// per-iteration pre-zeroed Sv buffers (the only cross-block data, 4KB/batch).
// No logs/exps in the sinkhorn loop at all. Barriers: 6 per reg iter (5 v + 1
// moments) = 18 total, relaxed-atomic spin (R5-proven, no L2 flush).
//
// ws (floats): [0..767] accum[3][16][16] | [1024..1535 as u32] barriers
//              | [1536..] Sv[15][16][1024]   (all prep-zeroed each launch)

#define BATCH 16
#define NPTS  1024
#define REG_ITERS 3
#define SK_ITERS  5
#define EPS 1e-5f
#define LOG2E 1.44269504088896f

#define WS_ACC  0
#define WS_BARU 1024          // u32 index into ws
#define WS_SV   1536
#define SV_STRIDE (BATCH * NPTS)   // per-buffer floats
#define PREP_FLOATS (WS_SV + REG_ITERS * SK_ITERS * SV_STRIDE)  // 247296 = 966*256

__device__ __forceinline__ float ld_coh(const float* p) {
    return __hip_atomic_load((float*)p, __ATOMIC_RELAXED, __HIP_MEMORY_SCOPE_AGENT);
}
__device__ __forceinline__ void add_coh(float* p, float v) {
    __hip_atomic_fetch_add(p, v, __ATOMIC_RELAXED, __HIP_MEMORY_SCOPE_AGENT);
}

// relaxed spin barrier (R5-proven): no acquire/release cache maintenance.
__device__ __forceinline__ void batch_barrier(unsigned* bar, unsigned target) {
    __syncthreads();
    if (threadIdx.x == 0) {
        __builtin_amdgcn_s_waitcnt(0);   // drain my stores/atomics to coherent point
        __hip_atomic_fetch_add(bar, 1u, __ATOMIC_RELAXED, __HIP_MEMORY_SCOPE_AGENT);
        while (__hip_atomic_load(bar, __ATOMIC_RELAXED, __HIP_MEMORY_SCOPE_AGENT) < target)
            __builtin_amdgcn_s_sleep(2);
    }
    __syncthreads();
    __asm__ __volatile__("" ::: "memory");
}

// weighted Kabsch from 16 accum moments + old T -> new T (12 floats)
__device__ void kabsch_svd(const float* ac, const float* Told, float* Tnew) {
    double Sw = ac[0];
    double Sa[3] = {ac[1], ac[2], ac[3]};
    double Sb[3] = {ac[4], ac[5], ac[6]};
    double D  = Sw + (double)EPS;
    double ca0 = Sa[0]/D, ca1 = Sa[1]/D, ca2 = Sa[2]/D;
    double cb0 = Sb[0]/D, cb1 = Sb[1]/D, cb2 = Sb[2]/D;
    double f  = (2.0 - Sw / D) / D;
    double Am[3][3];
    for (int m = 0; m < 3; ++m)
        for (int n = 0; n < 3; ++n)
            Am[m][n] = (double)ac[7 + m*3 + n] - f * Sa[m] * Sb[n];
    double S[3][3];
    for (int i = 0; i < 3; ++i)
        for (int j = 0; j < 3; ++j) {
            double a2 = 0;
            for (int m = 0; m < 3; ++m) a2 += Am[m][i] * Am[m][j];
            S[i][j] = a2;
        }
    double V[3][3] = {{1,0,0},{0,1,0},{0,0,1}};
    const int prr[3] = {0,0,1}, qrr[3] = {1,2,2};
    for (int sweep = 0; sweep < 25; ++sweep) {
        double off = S[0][1]*S[0][1] + S[0][2]*S[0][2] + S[1][2]*S[1][2];
        if (off < 1e-28) break;
        for (int pi = 0; pi < 3; ++pi) {
            int p = prr[pi], q = qrr[pi];
            double apq = S[p][q];
            if (fabs(apq) < 1e-300) continue;
            double theta = (S[q][q] - S[p][p]) / (2.0 * apq);
            double tt = ((theta >= 0) ? 1.0 : -1.0) / (fabs(theta) + sqrt(theta*theta + 1.0));
            double cth = 1.0 / sqrt(tt*tt + 1.0), sth = tt * cth;
            for (int m = 0; m < 3; ++m) { double a1=S[m][p], a2=S[m][q]; S[m][p]=cth*a1-sth*a2; S[m][q]=sth*a1+cth*a2; }
            for (int m = 0; m < 3; ++m) { double a1=S[p][m], a2=S[q][m]; S[p][m]=cth*a1-sth*a2; S[q][m]=sth*a1+cth*a2; }
            for (int m = 0; m < 3; ++m) { double a1=V[m][p], a2=V[m][q]; V[m][p]=cth*a1-sth*a2; V[m][q]=sth*a1+cth*a2; }
        }
    }
    double lam[3] = {S[0][0], S[1][1], S[2][2]};
    int idx[3] = {0,1,2};
    if (lam[idx[0]] < lam[idx[1]]) { int t2=idx[0]; idx[0]=idx[1]; idx[1]=t2; }
    if (lam[idx[0]] < lam[idx[2]]) { int t2=idx[0]; idx[0]=idx[2]; idx[2]=t2; }
    if (lam[idx[1]] < lam[idx[2]]) { int t2=idx[1]; idx[1]=idx[2]; idx[2]=t2; }
    double Vs[3][3], sv[3];
    for (int i = 0; i < 3; ++i) {
        int c = idx[i];
        for (int m = 0; m < 3; ++m) Vs[m][i] = V[m][c];
        double l = lam[c]; sv[i] = sqrt(l > 0 ? l : 0);
    }
    double Us[3][3] = {{1,0,0},{0,1,0},{0,0,1}};
    double smax = sv[0] > 1e-300 ? sv[0] : 1e-300;
    for (int i = 0; i < 3; ++i) {
        double ux = Am[0][0]*Vs[0][i] + Am[0][1]*Vs[1][i] + Am[0][2]*Vs[2][i];
        double uy = Am[1][0]*Vs[0][i] + Am[1][1]*Vs[1][i] + Am[1][2]*Vs[2][i];
        double uz = Am[2][0]*Vs[0][i] + Am[2][1]*Vs[1][i] + Am[2][2]*Vs[2][i];
        if (sv[i] > 1e-12 * smax) {
            Us[0][i] = ux/sv[i]; Us[1][i] = uy/sv[i]; Us[2][i] = uz/sv[i];
        } else if (i == 2) {
            double cx = Us[1][0]*Us[2][1] - Us[2][0]*Us[1][1];
            double cy = Us[2][0]*Us[0][1] - Us[0][0]*Us[2][1];
            double cz = Us[0][0]*Us[1][1] - Us[1][0]*Us[0][1];
            double n = sqrt(cx*cx + cy*cy + cz*cz); n = n > 1e-300 ? n : 1.0;
            Us[0][i] = cx/n; Us[1][i] = cy/n; Us[2][i] = cz/n;
        }
    }
    double M[3][3];
    for (int m = 0; m < 3; ++m)
        for (int n = 0; n < 3; ++n)
            M[m][n] = Vs[m][0]*Us[n][0] + Vs[m][1]*Us[n][1] + Vs[m][2]*Us[n][2];
    double det = M[0][0]*(M[1][1]*M[2][2]-M[1][2]*M[2][1])
               - M[0][1]*(M[1][0]*M[2][2]-M[1][2]*M[2][0])
               + M[0][2]*(M[1][0]*M[2][1]-M[1][1]*M[2][0]);
    double g3 = (det > 0.0) ? 1.0 : -1.0;
    double R[3][3];
    for (int m = 0; m < 3; ++m)
        for (int n = 0; n < 3; ++n)
            R[m][n] = Vs[m][0]*Us[n][0] + Vs[m][1]*Us[n][1] + g3*Vs[m][2]*Us[n][2];
    double ti[3];
    ti[0] = -(R[0][0]*ca0 + R[0][1]*ca1 + R[0][2]*ca2) + cb0;
    ti[1] = -(R[1][0]*ca0 + R[1][1]*ca1 + R[1][2]*ca2) + cb1;
    ti[2] = -(R[2][0]*ca0 + R[2][1]*ca1 + R[2][2]*ca2) + cb2;
    double Ro[3][3] = {{Told[0],Told[1],Told[2]},{Told[4],Told[5],Told[6]},{Told[8],Told[9],Told[10]}};
    double to[3] = {Told[3], Told[7], Told[11]};
    for (int m = 0; m < 3; ++m) {
        for (int n = 0; n < 3; ++n)
            Tnew[m*4+n] = (float)(R[m][0]*Ro[0][n] + R[m][1]*Ro[1][n] + R[m][2]*Ro[2][n]);
        Tnew[m*4+3] = (float)(R[m][0]*to[0] + R[m][1]*to[1] + R[m][2]*to[2] + ti[m]);
    }
}

__global__ __launch_bounds__(256) void prep_kernel(float* ws) {
    int i = blockIdx.x * 256 + threadIdx.x;   // grid 966 x 256 = 247296
    ws[i] = 0.f;
}

__global__ __launch_bounds__(256, 2) void rpm_kernel(
        const float* __restrict__ psrc, const float* __restrict__ pref,
        const float* __restrict__ beta, const float* __restrict__ alpha,
        float* __restrict__ ws, float* __restrict__ outT, float* __restrict__ perm)
{
    __shared__ float refL[NPTS * 7];   // 28 KB: x,y,z,f3,f4,f5,sq  (stride 7: conflict-free)
    __shared__ float sred[4][16];
    __shared__ float tT[12];
    __shared__ float tTn[12];

    const int blk = blockIdx.x, b = blk & 15, sub = blk >> 4;
    const int tid = threadIdx.x, wid = tid >> 6, lane = tid & 63;
    const int rbase = (sub << 5) + (wid << 3);
    const int grow  = (b << 10) + rbase;

    float*    accA = ws + WS_ACC;
    unsigned* bar  = (unsigned*)ws + WS_BARU + b * 32;
    float*    svA  = ws + WS_SV;
    unsigned  phase = 0;

    const float bet2 = beta[b] * LOG2E;
    const float alp  = alpha[b];
    const float tb2  = 2.f * bet2;

    // ---- stage ref features to LDS (block-local)
    for (int i = tid; i < NPTS; i += 256) {
        const float* p = pref + ((size_t)(b << 10) + i) * 6;
        float x=p[0], y=p[1], z=p[2], aa=p[3], bb=p[4], cc=p[5];
        float* o = refL + i * 7;
        o[0]=x; o[1]=y; o[2]=z; o[3]=aa; o[4]=bb; o[5]=cc;
        o[6] = x*x + y*y + z*z + aa*aa + bb*bb + cc*cc;
    }
    if (tid < 12) tT[tid] = (tid == 0 || tid == 5 || tid == 10) ? 1.f : 0.f;
    __syncthreads();

    float Kreg[8][16];      // this lane's K[r][k=lane+64i], persistent per reg iter
    float rx[8], ry[8], rz[8];
    float wu[8];

    for (int it = 0; it < REG_ITERS; ++it) {
        const bool last = (it == REG_ITERS - 1);

        // ---- A) K-build: transform own rows, K = exp2(aff2) into registers
        {
            float f3[8], f4[8], f5[8], cr[8];
            #pragma unroll
            for (int r = 0; r < 8; ++r) {
                const float* p = psrc + (size_t)(grow + r) * 6;
                float x = p[0], y = p[1], z = p[2];
                float tx = tT[0]*x + tT[1]*y + tT[2]*z  + tT[3];
                float ty = tT[4]*x + tT[5]*y + tT[6]*z  + tT[7];
                float tz = tT[8]*x + tT[9]*y + tT[10]*z + tT[11];
                f3[r] = p[3]; f4[r] = p[4]; f5[r] = p[5];
                rx[r] = tx; ry[r] = ty; rz[r] = tz;
                float sq = tx*tx + ty*ty + tz*tz + f3[r]*f3[r] + f4[r]*f4[r] + f5[r]*f5[r];
                cr[r] = bet2 * (alp - sq);
            }
            #pragma unroll
            for (int i = 0; i < 16; ++i) {
                const float* L = refL + (lane + 64*i) * 7;
                float r0=L[0], r1=L[1], r2=L[2], r3=L[3], r4=L[4], r5=L[5];
                float tk = bet2 * L[6];
                #pragma unroll
                for (int r = 0; r < 8; ++r) {
                    float d = rx[r]*r0 + ry[r]*r1 + rz[r]*r2
                            + f3[r]*r3 + f4[r]*r4 + f5[r]*r5;
                    Kreg[r][i] = __builtin_amdgcn_exp2f(fmaf(tb2, d, cr[r] - tk));
                }
            }
        }

        // ---- B) 5 x (u-pass local, v-pass -> atomic Sv, barrier)
        for (int sk = 0; sk < SK_ITERS; ++sk) {
            float Su[8];
            #pragma unroll
            for (int r = 0; r < 8; ++r) Su[r] = 0.f;
            if (sk == 0) {
                #pragma unroll
                for (int i = 0; i < 16; ++i)
                    #pragma unroll
                    for (int r = 0; r < 8; ++r) Su[r] += Kreg[r][i];
            } else {
                const float* sb = svA + (it*SK_ITERS + sk - 1) * SV_STRIDE + (b << 10);
                float wv[16];
                #pragma unroll
                for (int i = 0; i < 16; ++i)
                    wv[i] = __builtin_amdgcn_rcpf(1.f + ld_coh(sb + lane + 64*i));
                #pragma unroll
                for (int i = 0; i < 16; ++i)
                    #pragma unroll
                    for (int r = 0; r < 8; ++r) Su[r] += Kreg[r][i] * wv[i];
            }
            #pragma unroll
            for (int r = 0; r < 8; ++r) {
                float a = Su[r];
                for (int off = 32; off; off >>= 1) a += __shfl_down(a, off);
                wu[r] = __builtin_amdgcn_rcpf(1.f + __shfl(a, 0));
            }
            // v-pass: column partials from registers -> atomicAdd
            float* vb = svA + (it*SK_ITERS + sk) * SV_STRIDE + (b << 10);
            #pragma unroll
            for (int i = 0; i < 16; ++i) {
                float pv = 0.f;
                #pragma unroll
                for (int r = 0; r < 8; ++r) pv += Kreg[r][i] * wu[r];
                add_coh(vb + lane + 64*i, pv);
            }
            batch_barrier(bar, 32u * (++phase));
        }

        // ---- C) finalize: perm (last iter) + moment accumulators
        {
            const float* sb = svA + (it*SK_ITERS + SK_ITERS - 1) * SV_STRIDE + (b << 10);
            float wv[16];
            #pragma unroll
            for (int i = 0; i < 16; ++i)
                wv[i] = __builtin_amdgcn_rcpf(1.f + ld_coh(sb + lane + 64*i));
            float pS[16];
            #pragma unroll
            for (int i2 = 0; i2 < 16; ++i2) pS[i2] = 0.f;
            for (int r = 0; r < 8; ++r) {
                float s=0.f, smx=0.f, smy=0.f, smz=0.f;
                const float w = wu[r];
                #pragma unroll
                for (int i = 0; i < 16; ++i) {
                    int k = lane + 64*i;
                    float p = Kreg[r][i] * w * wv[i];
                    const float* L = refL + k * 7;
                    s += p; smx += p*L[0]; smy += p*L[1]; smz += p*L[2];
                    if (last) perm[(size_t)(grow + r) * NPTS + k] = p;
                }
                for (int off = 32; off; off >>= 1) {
                    s   += __shfl_down(s,   off);
                    smx += __shfl_down(smx, off);
                    smy += __shfl_down(smy, off);
                    smz += __shfl_down(smz, off);
                }
                if (lane == 0) {
                    float inv = 1.f / (s + EPS);
                    float bx = smx*inv, by = smy*inv, bz = smz*inv;
                    float fx = rx[r], fy = ry[r], fz = rz[r];
                    pS[0] += s;
                    pS[1] += s*fx;  pS[2] += s*fy;  pS[3] += s*fz;
                    pS[4] += s*bx;  pS[5] += s*by;  pS[6] += s*bz;
                    pS[7] += s*fx*bx;  pS[8]  += s*fx*by;  pS[9]  += s*fx*bz;
                    pS[10]+= s*fy*bx;  pS[11] += s*fy*by;  pS[12] += s*fy*bz;
                    pS[13]+= s*fz*bx;  pS[14] += s*fz*by;  pS[15] += s*fz*bz;
                }
            }
            if (lane == 0) {
                #pragma unroll
                for (int i2 = 0; i2 < 16; ++i2) sred[wid][i2] = pS[i2];
            }
            __syncthreads();
            float* ac = accA + it * 256 + b * 16;
            if (tid < 16)
                add_coh(&ac[tid], sred[0][tid] + sred[1][tid] + sred[2][tid] + sred[3][tid]);
            batch_barrier(bar, 32u * (++phase));

            // ---- D) SVD redundantly per block from identical accum bits
            if (!last || sub == 0) {
                if (tid == 0) {
                    float acl[16];
                    #pragma unroll
                    for (int i2 = 0; i2 < 16; ++i2) acl[i2] = ld_coh(&ac[i2]);
                    float Tl[12];
                    #pragma unroll
                    for (int i2 = 0; i2 < 12; ++i2) Tl[i2] = tT[i2];
                    kabsch_svd(acl, Tl, tTn);
                }
                __syncthreads();
                if (tid < 12) tT[tid] = tTn[tid];
                __syncthreads();
                if (last && tid == 0) {
                    #pragma unroll
                    for (int i2 = 0; i2 < 12; ++i2) outT[b * 12 + i2] = tT[i2];
                }
            }
        }
    }
}

extern "C" void kernel_launch(void* const* d_in, const int* in_sizes, int n_in,
                              void* d_out, int out_size, void* d_ws, size_t ws_size,
                              hipStream_t stream) {
    const float* psrc  = (const float*)d_in[0];
    const float* pref  = (const float*)d_in[1];
    const float* beta  = (const float*)d_in[2];
    const float* alpha = (const float*)d_in[3];

    float* out     = (float*)d_out;
    float* outT    = out;            // (16,3,4)
    float* outPerm = out + 192;      // (16,1024,1024)
    float* ws      = (float*)d_ws;

    prep_kernel<<<PREP_FLOATS / 256, 256, 0, stream>>>(ws);

    void* args[] = { (void*)&psrc, (void*)&pref, (void*)&beta, (void*)&alpha,
                     (void*)&ws, (void*)&outT, (void*)&outPerm };
    hipError_t ce = hipLaunchCooperativeKernel((const void*)rpm_kernel, dim3(512), dim3(256),
                                               args, 0, stream);
    if (ce != hipSuccess) {
        rpm_kernel<<<dim3(512), dim3(256), 0, stream>>>(psrc, pref, beta, alpha,
                                                        ws, outT, outPerm);
    }
}

// Round 7
// 410.022 us; speedup vs baseline: 3.4687x; 1.2418x over previous
//
#include <hip/hip_runtime.h>
#include <hip/hip_fp16.h>
#include <math.h>

// RPMNet registration, fused persistent kernel, linear-domain Sinkhorn with
// REGISTER-RESIDENT fp16 K. B=16, N=1024, feat 6; 3 reg iters x 5 sk iters.
// Each block owns 32 rows of one batch; per lane K is __half2 Kh[8][8] (64 VGPRs).
// wu = 1/(1+K@wv) block-local; wv via per-block LDS pre-reduce + one relaxed
// agent-scope fp32 atomicAdd per column per block into per-iteration pre-zeroed
// Sv buffers. No L2-flushing sync anywhere (R5/R6-proven relaxed barrier).
// amdgpu_waves_per_eu(2,2) pins 2 waves/EU => 256-VGPR budget => no K spill.
//
// ws (floats): [0..767] accum[3][16][16] | [1024..1535 as u32] barriers
//              | [1536..] Sv[15][16][1024]   (all prep-zeroed each launch)

#define BATCH 16
#define NPTS  1024
#define REG_ITERS 3
#define SK_ITERS  5
#define EPS 1e-5f
#define LOG2E 1.44269504088896f

#define WS_ACC  0
#define WS_BARU 1024
#define WS_SV   1536
#define SV_STRIDE (BATCH * NPTS)
#define PREP_FLOATS (WS_SV + REG_ITERS * SK_ITERS * SV_STRIDE)  // 247296 = 966*256

__device__ __forceinline__ float ld_coh(const float* p) {
    return __hip_atomic_load((float*)p, __ATOMIC_RELAXED, __HIP_MEMORY_SCOPE_AGENT);
}
__device__ __forceinline__ void add_coh(float* p, float v) {
    __hip_atomic_fetch_add(p, v, __ATOMIC_RELAXED, __HIP_MEMORY_SCOPE_AGENT);
}

// relaxed spin barrier (R5/R6-proven): no acquire/release cache maintenance.
__device__ __forceinline__ void batch_barrier(unsigned* bar, unsigned target) {
    __syncthreads();
    if (threadIdx.x == 0) {
        __builtin_amdgcn_s_waitcnt(0);   // drain my stores/atomics to coherent point
        __hip_atomic_fetch_add(bar, 1u, __ATOMIC_RELAXED, __HIP_MEMORY_SCOPE_AGENT);
        while (__hip_atomic_load(bar, __ATOMIC_RELAXED, __HIP_MEMORY_SCOPE_AGENT) < target)
            __builtin_amdgcn_s_sleep(2);
    }
    __syncthreads();
    __asm__ __volatile__("" ::: "memory");
}

// weighted Kabsch from 16 accum moments + old T -> new T (12 floats)
__device__ void kabsch_svd(const float* ac, const float* Told, float* Tnew) {
    double Sw = ac[0];
    double Sa[3] = {ac[1], ac[2], ac[3]};
    double Sb[3] = {ac[4], ac[5], ac[6]};
    double D  = Sw + (double)EPS;
    double ca0 = Sa[0]/D, ca1 = Sa[1]/D, ca2 = Sa[2]/D;
    double cb0 = Sb[0]/D, cb1 = Sb[1]/D, cb2 = Sb[2]/D;
    double f  = (2.0 - Sw / D) / D;
    double Am[3][3];
    for (int m = 0; m < 3; ++m)
        for (int n = 0; n < 3; ++n)
            Am[m][n] = (double)ac[7 + m*3 + n] - f * Sa[m] * Sb[n];
    double S[3][3];
    for (int i = 0; i < 3; ++i)
        for (int j = 0; j < 3; ++j) {
            double a2 = 0;
            for (int m = 0; m < 3; ++m) a2 += Am[m][i] * Am[m][j];
            S[i][j] = a2;
        }
    double V[3][3] = {{1,0,0},{0,1,0},{0,0,1}};
    const int prr[3] = {0,0,1}, qrr[3] = {1,2,2};
    for (int sweep = 0; sweep < 25; ++sweep) {
        double off = S[0][1]*S[0][1] + S[0][2]*S[0][2] + S[1][2]*S[1][2];
        if (off < 1e-28) break;
        for (int pi = 0; pi < 3; ++pi) {
            int p = prr[pi], q = qrr[pi];
            double apq = S[p][q];
            if (fabs(apq) < 1e-300) continue;
            double theta = (S[q][q] - S[p][p]) / (2.0 * apq);
            double tt = ((theta >= 0) ? 1.0 : -1.0) / (fabs(theta) + sqrt(theta*theta + 1.0));
            double cth = 1.0 / sqrt(tt*tt + 1.0), sth = tt * cth;
            for (int m = 0; m < 3; ++m) { double a1=S[m][p], a2=S[m][q]; S[m][p]=cth*a1-sth*a2; S[m][q]=sth*a1+cth*a2; }
            for (int m = 0; m < 3; ++m) { double a1=S[p][m], a2=S[q][m]; S[p][m]=cth*a1-sth*a2; S[q][m]=sth*a1+cth*a2; }
            for (int m = 0; m < 3; ++m) { double a1=V[m][p], a2=V[m][q]; V[m][p]=cth*a1-sth*a2; V[m][q]=sth*a1+cth*a2; }
        }
    }
    double lam[3] = {S[0][0], S[1][1], S[2][2]};
    int idx[3] = {0,1,2};
    if (lam[idx[0]] < lam[idx[1]]) { int t2=idx[0]; idx[0]=idx[1]; idx[1]=t2; }
    if (lam[idx[0]] < lam[idx[2]]) { int t2=idx[0]; idx[0]=idx[2]; idx[2]=t2; }
    if (lam[idx[1]] < lam[idx[2]]) { int t2=idx[1]; idx[1]=idx[2]; idx[2]=t2; }
    double Vs[3][3], sv[3];
    for (int i = 0; i < 3; ++i) {
        int c = idx[i];
        for (int m = 0; m < 3; ++m) Vs[m][i] = V[m][c];
        double l = lam[c]; sv[i] = sqrt(l > 0 ? l : 0);
    }
    double Us[3][3] = {{1,0,0},{0,1,0},{0,0,1}};
    double smax = sv[0] > 1e-300 ? sv[0] : 1e-300;
    for (int i = 0; i < 3; ++i) {
        double ux = Am[0][0]*Vs[0][i] + Am[0][1]*Vs[1][i] + Am[0][2]*Vs[2][i];
        double uy = Am[1][0]*Vs[0][i] + Am[1][1]*Vs[1][i] + Am[1][2]*Vs[2][i];
        double uz = Am[2][0]*Vs[0][i] + Am[2][1]*Vs[1][i] + Am[2][2]*Vs[2][i];
        if (sv[i] > 1e-12 * smax) {
            Us[0][i] = ux/sv[i]; Us[1][i] = uy/sv[i]; Us[2][i] = uz/sv[i];
        } else if (i == 2) {
            double cx = Us[1][0]*Us[2][1] - Us[2][0]*Us[1][1];
            double cy = Us[2][0]*Us[0][1] - Us[0][0]*Us[2][1];
            double cz = Us[0][0]*Us[1][1] - Us[1][0]*Us[0][1];
            double n = sqrt(cx*cx + cy*cy + cz*cz); n = n > 1e-300 ? n : 1.0;
            Us[0][i] = cx/n; Us[1][i] = cy/n; Us[2][i] = cz/n;
        }
    }
    double M[3][3];
    for (int m = 0; m < 3; ++m)
        for (int n = 0; n < 3; ++n)
            M[m][n] = Vs[m][0]*Us[n][0] + Vs[m][1]*Us[n][1] + Vs[m][2]*Us[n][2];
    double det = M[0][0]*(M[1][1]*M[2][2]-M[1][2]*M[2][1])
               - M[0][1]*(M[1][0]*M[2][2]-M[1][2]*M[2][0])
               + M[0][2]*(M[1][0]*M[2][1]-M[1][1]*M[2][0]);
    double g3 = (det > 0.0) ? 1.0 : -1.0;
    double R[3][3];
    for (int m = 0; m < 3; ++m)
        for (int n = 0; n < 3; ++n)
            R[m][n] = Vs[m][0]*Us[n][0] + Vs[m][1]*Us[n][1] + g3*Vs[m][2]*Us[n][2];
    double ti[3];
    ti[0] = -(R[0][0]*ca0 + R[0][1]*ca1 + R[0][2]*ca2) + cb0;
    ti[1] = -(R[1][0]*ca0 + R[1][1]*ca1 + R[1][2]*ca2) + cb1;
    ti[2] = -(R[2][0]*ca0 + R[2][1]*ca1 + R[2][2]*ca2) + cb2;
    double Ro[3][3] = {{Told[0],Told[1],Told[2]},{Told[4],Told[5],Told[6]},{Told[8],Told[9],Told[10]}};
    double to[3] = {Told[3], Told[7], Told[11]};
    for (int m = 0; m < 3; ++m) {
        for (int n = 0; n < 3; ++n)
            Tnew[m*4+n] = (float)(R[m][0]*Ro[0][n] + R[m][1]*Ro[1][n] + R[m][2]*Ro[2][n]);
        Tnew[m*4+3] = (float)(R[m][0]*to[0] + R[m][1]*to[1] + R[m][2]*to[2] + ti[m]);
    }
}

__global__ __launch_bounds__(256) void prep_kernel(float* ws) {
    int i = blockIdx.x * 256 + threadIdx.x;   // grid 966 x 256
    ws[i] = 0.f;
}

__global__
__attribute__((amdgpu_flat_work_group_size(256, 256), amdgpu_waves_per_eu(2, 2)))
void rpm_kernel(
        const float* __restrict__ psrc, const float* __restrict__ pref,
        const float* __restrict__ beta, const float* __restrict__ alpha,
        float* __restrict__ ws, float* __restrict__ outT, float* __restrict__ perm)
{
    __shared__ float refL[NPTS * 7];     // 28 KB: x,y,z,f3,f4,f5,sq (stride 7)
    __shared__ float svp[4][NPTS];       // 16 KB: per-wave column partials
    __shared__ float sred[4][16];
    __shared__ float tT[12];
    __shared__ float tTn[12];

    const int blk = blockIdx.x, b = blk & 15, sub = blk >> 4;
    const int tid = threadIdx.x, wid = tid >> 6, lane = tid & 63;
    const int rbase = (sub << 5) + (wid << 3);
    const int grow  = (b << 10) + rbase;

    float*    accA = ws + WS_ACC;
    unsigned* bar  = (unsigned*)ws + WS_BARU + b * 32;
    float*    svA  = ws + WS_SV;
    unsigned  phase = 0;

    const float bet2 = beta[b] * LOG2E;
    const float alp  = alpha[b];
    const float tb2  = 2.f * bet2;

    // ---- stage ref features to LDS (block-local)
    for (int i = tid; i < NPTS; i += 256) {
        const float* p = pref + ((size_t)(b << 10) + i) * 6;
        float x=p[0], y=p[1], z=p[2], aa=p[3], bb=p[4], cc=p[5];
        float* o = refL + i * 7;
        o[0]=x; o[1]=y; o[2]=z; o[3]=aa; o[4]=bb; o[5]=cc;
        o[6] = x*x + y*y + z*z + aa*aa + bb*bb + cc*cc;
    }
    if (tid < 12) tT[tid] = (tid == 0 || tid == 5 || tid == 10) ? 1.f : 0.f;
    __syncthreads();

    __half2 Kh[8][8];    // K[r][col = lane + 64*(2j) .. +64] packed fp16x2 (64 VGPRs)
    float wu[8];

    for (int it = 0; it < REG_ITERS; ++it) {
        const bool last = (it == REG_ITERS - 1);

        // ---- A) K-build: transform own rows, K = exp2(aff2) -> fp16 registers
        {
            float rx[8], ry[8], rz[8], f3[8], f4[8], f5[8], cr[8];
            #pragma unroll
            for (int r = 0; r < 8; ++r) {
                const float* p = psrc + (size_t)(grow + r) * 6;
                float x = p[0], y = p[1], z = p[2];
                float tx = tT[0]*x + tT[1]*y + tT[2]*z  + tT[3];
                float ty = tT[4]*x + tT[5]*y + tT[6]*z  + tT[7];
                float tz = tT[8]*x + tT[9]*y + tT[10]*z + tT[11];
                f3[r] = p[3]; f4[r] = p[4]; f5[r] = p[5];
                rx[r] = tx; ry[r] = ty; rz[r] = tz;
                float sq = tx*tx + ty*ty + tz*tz + f3[r]*f3[r] + f4[r]*f4[r] + f5[r]*f5[r];
                cr[r] = bet2 * (alp - sq);
            }
            #pragma unroll
            for (int j = 0; j < 8; ++j) {
                const float* L0 = refL + (lane + 128*j) * 7;
                const float* L1 = L0 + 64 * 7;
                float a0=L0[0], a1=L0[1], a2=L0[2], a3=L0[3], a4=L0[4], a5=L0[5];
                float c0=L1[0], c1=L1[1], c2=L1[2], c3=L1[3], c4=L1[4], c5=L1[5];
                float tk0 = bet2 * L0[6], tk1 = bet2 * L1[6];
                #pragma unroll
                for (int r = 0; r < 8; ++r) {
                    float d0 = rx[r]*a0 + ry[r]*a1 + rz[r]*a2 + f3[r]*a3 + f4[r]*a4 + f5[r]*a5;
                    float d1 = rx[r]*c0 + ry[r]*c1 + rz[r]*c2 + f3[r]*c3 + f4[r]*c4 + f5[r]*c5;
                    float k0 = __builtin_amdgcn_exp2f(fmaf(tb2, d0, cr[r] - tk0));
                    float k1 = __builtin_amdgcn_exp2f(fmaf(tb2, d1, cr[r] - tk1));
                    Kh[r][j] = __floats2half2_rn(k0, k1);
                }
            }
        }

        // ---- B) 5 x (u-pass local, v-pass -> LDS pre-reduce -> atomic Sv)
        for (int sk = 0; sk < SK_ITERS; ++sk) {
            float Su[8];
            #pragma unroll
            for (int r = 0; r < 8; ++r) Su[r] = 0.f;
            if (sk == 0) {
                #pragma unroll
                for (int j = 0; j < 8; ++j)
                    #pragma unroll
                    for (int r = 0; r < 8; ++r) {
                        float2 kk = __half22float2(Kh[r][j]);
                        Su[r] += kk.x + kk.y;
                    }
            } else {
                const float* sb = svA + (it*SK_ITERS + sk - 1) * SV_STRIDE + (b << 10);
                float wv0[8], wv1[8];
                #pragma unroll
                for (int j = 0; j < 8; ++j) {
                    wv0[j] = __builtin_amdgcn_rcpf(1.f + ld_coh(sb + lane + 128*j));
                    wv1[j] = __builtin_amdgcn_rcpf(1.f + ld_coh(sb + lane + 128*j + 64));
                }
                #pragma unroll
                for (int j = 0; j < 8; ++j)
                    #pragma unroll
                    for (int r = 0; r < 8; ++r) {
                        float2 kk = __half22float2(Kh[r][j]);
                        Su[r] = fmaf(kk.x, wv0[j], fmaf(kk.y, wv1[j], Su[r]));
                    }
            }
            #pragma unroll
            for (int r = 0; r < 8; ++r) {
                float a = Su[r];
                for (int off = 32; off; off >>= 1) a += __shfl_down(a, off);
                wu[r] = __builtin_amdgcn_rcpf(1.f + __shfl(a, 0));
            }
            // v-pass: per-wave column partials -> LDS -> cross-wave reduce -> atomic
            #pragma unroll
            for (int j = 0; j < 8; ++j) {
                float p0 = 0.f, p1 = 0.f;
                #pragma unroll
                for (int r = 0; r < 8; ++r) {
                    float2 kk = __half22float2(Kh[r][j]);
                    p0 = fmaf(kk.x, wu[r], p0);
                    p1 = fmaf(kk.y, wu[r], p1);
                }
                svp[wid][lane + 128*j]      = p0;
                svp[wid][lane + 128*j + 64] = p1;
            }
            __syncthreads();
            float* vb = svA + (it*SK_ITERS + sk) * SV_STRIDE + (b << 10);
            #pragma unroll
            for (int c0 = 0; c0 < 4; ++c0) {
                int c = tid + 256*c0;
                add_coh(vb + c, svp[0][c] + svp[1][c] + svp[2][c] + svp[3][c]);
            }
            batch_barrier(bar, 32u * (++phase));
        }

        // ---- C) finalize: perm (last iter) + moment accumulators
        {
            const float* sb = svA + (it*SK_ITERS + SK_ITERS - 1) * SV_STRIDE + (b << 10);
            float wv0[8], wv1[8];
            #pragma unroll
            for (int j = 0; j < 8; ++j) {
                wv0[j] = __builtin_amdgcn_rcpf(1.f + ld_coh(sb + lane + 128*j));
                wv1[j] = __builtin_amdgcn_rcpf(1.f + ld_coh(sb + lane + 128*j + 64));
            }
            // recompute transformed src coords (freed from registers during sinkhorn)
            float rx[8], ry[8], rz[8];
            #pragma unroll
            for (int r = 0; r < 8; ++r) {
                const float* p = psrc + (size_t)(grow + r) * 6;
                float x = p[0], y = p[1], z = p[2];
                rx[r] = tT[0]*x + tT[1]*y + tT[2]*z  + tT[3];
                ry[r] = tT[4]*x + tT[5]*y + tT[6]*z  + tT[7];
                rz[r] = tT[8]*x + tT[9]*y + tT[10]*z + tT[11];
            }
            float pS[16];
            #pragma unroll
            for (int i2 = 0; i2 < 16; ++i2) pS[i2] = 0.f;
            for (int r = 0; r < 8; ++r) {
                float s=0.f, smx=0.f, smy=0.f, smz=0.f;
                const float w = wu[r];
                #pragma unroll
                for (int j = 0; j < 8; ++j) {
                    int k0 = lane + 128*j, k1 = k0 + 64;
                    float2 kk = __half22float2(Kh[r][j]);
                    float p0 = kk.x * w * wv0[j];
                    float p1 = kk.y * w * wv1[j];
                    const float* L0 = refL + k0 * 7;
                    const float* L1 = refL + k1 * 7;
                    s += p0 + p1;
                    smx += p0*L0[0] + p1*L1[0];
                    smy += p0*L0[1] + p1*L1[1];
                    smz += p0*L0[2] + p1*L1[2];
                    if (last) {
                        perm[(size_t)(grow + r) * NPTS + k0] = p0;
                        perm[(size_t)(grow + r) * NPTS + k1] = p1;
                    }
                }
                for (int off = 32; off; off >>= 1) {
                    s   += __shfl_down(s,   off);
                    smx += __shfl_down(smx, off);
                    smy += __shfl_down(smy, off);
                    smz += __shfl_down(smz, off);
                }
                if (lane == 0) {
                    float inv = 1.f / (s + EPS);
                    float bx = smx*inv, by = smy*inv, bz = smz*inv;
                    float fx = rx[r], fy = ry[r], fz = rz[r];
                    pS[0] += s;
                    pS[1] += s*fx;  pS[2] += s*fy;  pS[3] += s*fz;
                    pS[4] += s*bx;  pS[5] += s*by;  pS[6] += s*bz;
                    pS[7] += s*fx*bx;  pS[8]  += s*fx*by;  pS[9]  += s*fx*bz;
                    pS[10]+= s*fy*bx;  pS[11] += s*fy*by;  pS[12] += s*fy*bz;
                    pS[13]+= s*fz*bx;  pS[14] += s*fz*by;  pS[15] += s*fz*bz;
                }
            }
            if (lane == 0) {
                #pragma unroll
                for (int i2 = 0; i2 < 16; ++i2) sred[wid][i2] = pS[i2];
            }
            __syncthreads();
            float* ac = accA + it * 256 + b * 16;
            if (tid < 16)
                add_coh(&ac[tid], sred[0][tid] + sred[1][tid] + sred[2][tid] + sred[3][tid]);
            batch_barrier(bar, 32u * (++phase));

            // ---- D) SVD redundantly per block from identical accum bits
            if (!last || sub == 0) {
                if (tid == 0) {
                    float acl[16];
                    #pragma unroll
                    for (int i2 = 0; i2 < 16; ++i2) acl[i2] = ld_coh(&ac[i2]);
                    float Tl[12];
                    #pragma unroll
                    for (int i2 = 0; i2 < 12; ++i2) Tl[i2] = tT[i2];
                    kabsch_svd(acl, Tl, tTn);
                }
                __syncthreads();
                if (tid < 12) tT[tid] = tTn[tid];
                __syncthreads();
                if (last && tid == 0) {
                    #pragma unroll
                    for (int i2 = 0; i2 < 12; ++i2) outT[b * 12 + i2] = tT[i2];
                }
            }
        }
    }
}

extern "C" void kernel_launch(void* const* d_in, const int* in_sizes, int n_in,
                              void* d_out, int out_size, void* d_ws, size_t ws_size,
                              hipStream_t stream) {
    const float* psrc  = (const float*)d_in[0];
    const float* pref  = (const float*)d_in[1];
    const float* beta  = (const float*)d_in[2];
    const float* alpha = (const float*)d_in[3];

    float* out     = (float*)d_out;
    float* outT    = out;            // (16,3,4)
    float* outPerm = out + 192;      // (16,1024,1024)
    float* ws      = (float*)d_ws;

    prep_kernel<<<PREP_FLOATS / 256, 256, 0, stream>>>(ws);

    void* args[] = { (void*)&psrc, (void*)&pref, (void*)&beta, (void*)&alpha,
                     (void*)&ws, (void*)&outT, (void*)&outPerm };
    hipError_t ce = hipLaunchCooperativeKernel((const void*)rpm_kernel, dim3(512), dim3(256),
                                               args, 0, stream);
    if (ce != hipSuccess) {
        rpm_kernel<<<dim3(512), dim3(256), 0, stream>>>(psrc, pref, beta, alpha,
                                                        ws, outT, outPerm);
    }
}